// Round 8
// baseline (108.709 us; speedup 1.0000x reference)
//
#include <hip/hip_runtime.h>

// FDN reverb == 8-tap sparse FIR + 50/50 mix + global max-abs normalize.
// Plain stream-ordered two-pass (cooperative grid.sync measured ~100us of
// overhead in R3/R4 — do not use):
//   pass A: LDS-staged FIR, block max only -> slots[blk]  (no 32MB store)
//   pass B: reduce slots -> 1/max, recompute FIR, scale, single 32MB write
// LDS reads exploit delay parity: D1,D2,D6 = 0 mod 4 -> ds_read_b128,
// D4 = 2 mod 4 -> 2x ds_read_b64, D0,D3,D5,D7 = 1 mod 4 -> b32+b64+b32.
// CHUNK=8192: halo (3840) re-read overhead halves vs 4096; 48KB LDS ->
// 3 blocks/CU (12 waves) still hides LDS/VMEM latency.
// Block swizzle: give each XCD a contiguous 4MB region of x (== its L2).
#define T_LEN 8388608
#define CHUNK 8192               // outputs per block
#define HALO  3840               // >= max delay (3825), multiple of 4
#define LDSF  (HALO + CHUNK)     // 12032 floats = 48128 B -> 3 blocks/CU
#define NBLK  (T_LEN / CHUNK)    // 1024 blocks

#define D0 1425   // %4 == 1
#define D1 1780   // %4 == 0
#define D2 1972   // %4 == 0
#define D3 2097   // %4 == 1
#define D4 2558   // %4 == 2
#define D5 2961   // %4 == 1
#define D6 3508   // %4 == 0
#define D7 3825   // %4 == 1

typedef float floatx4 __attribute__((ext_vector_type(4)));  // native vec for
                                                            // nontemporal store

__device__ __forceinline__ int swz(int b) {
    // phys block -> logical chunk: XCD k (b%8) owns contiguous [k*128,(k+1)*128)
    return (b & 7) * (NBLK / 8) + (b >> 3);
}

__device__ __forceinline__ void load_odd(const float* q, float* v) {
    // q is (3 mod 4)-dword aligned: scalar, aligned float2, scalar
    float  a  = q[0];
    float2 b  = *(const float2*)(q + 1);
    float  c  = q[3];
    v[0] = a; v[1] = b.x; v[2] = b.y; v[3] = c;
}

// Compute 4 outputs at LDS pointer p (16B-aligned), coefficients c[8].
__device__ __forceinline__ float4 quad_fir(const float* __restrict__ p,
                                           const float* __restrict__ c) {
    float4 dry = *(const float4*)(p);
    float4 t1  = *(const float4*)(p - D1);   // b128
    float4 t2  = *(const float4*)(p - D2);   // b128
    float4 t6  = *(const float4*)(p - D6);   // b128
    float2 t4a = *(const float2*)(p - D4);   // b64 (p-D4 is 2 mod 4)
    float2 t4b = *(const float2*)(p - D4 + 2);
    float t0v[4], t3v[4], t5v[4], t7v[4];
    load_odd(p - D0, t0v);
    load_odd(p - D3, t3v);
    load_odd(p - D5, t5v);
    load_odd(p - D7, t7v);
    float t4v[4] = {t4a.x, t4a.y, t4b.x, t4b.y};

    float4 o;
#pragma unroll
    for (int k = 0; k < 4; ++k) {
        float wet = 0.f;
        wet = fmaf(c[0], t0v[k],      wet);
        wet = fmaf(c[1], (&t1.x)[k],  wet);
        wet = fmaf(c[2], (&t2.x)[k],  wet);
        wet = fmaf(c[3], t3v[k],      wet);
        wet = fmaf(c[4], t4v[k],      wet);
        wet = fmaf(c[5], t5v[k],      wet);
        wet = fmaf(c[6], (&t6.x)[k],  wet);
        wet = fmaf(c[7], t7v[k],      wet);
        (&o.x)[k] = fmaf(0.5f, wet, 0.5f * (&dry.x)[k]);
    }
    return o;
}

// Stage [blk*CHUNK - HALO, blk*CHUNK + CHUNK) into LDS; zeros before t=0.
__device__ __forceinline__ void stage(const float* __restrict__ x, float* smem,
                                      int blk, int tid) {
    const long gs = (long)blk * CHUNK - HALO;
    for (int v4 = tid; v4 < LDSF / 4; v4 += 256) {
        long ga = gs + (long)v4 * 4;
        float4 val = make_float4(0.f, 0.f, 0.f, 0.f);
        if (ga >= 0) val = *(const float4*)(x + ga);
        *(float4*)(smem + v4 * 4) = val;
    }
}

__device__ __forceinline__ void load_coeffs(const float* __restrict__ g,
                                            const float* __restrict__ Q,
                                            float* csh, int tid) {
    if (tid < 8) {
        float s = 0.f;
#pragma unroll
        for (int j = 0; j < 8; ++j) s += Q[j * 8 + tid];
        csh[tid] = s * g[tid];
    }
}

// Pass A: FIR + block max -> slots[blk]. No output store.
__global__ __launch_bounds__(256) void fdn_max(
    const float* __restrict__ x, const float* __restrict__ g,
    const float* __restrict__ Q, float* __restrict__ slots) {
    __shared__ __align__(16) float smem[LDSF];
    __shared__ float csh[8];
    __shared__ float wmax[4];

    const int tid = threadIdx.x;
    const int blk = swz(blockIdx.x);

    load_coeffs(g, Q, csh, tid);
    stage(x, smem, blk, tid);
    __syncthreads();

    float c[8];
#pragma unroll
    for (int n = 0; n < 8; ++n) c[n] = csh[n];

    float m = 0.f;
#pragma unroll
    for (int i = 0; i < CHUNK / 1024; ++i) {
        const float* p = smem + HALO + i * 1024 + tid * 4;
        float4 o = quad_fir(p, c);
        m = fmaxf(m, fmaxf(fmaxf(fabsf(o.x), fabsf(o.y)),
                           fmaxf(fabsf(o.z), fabsf(o.w))));
    }

#pragma unroll
    for (int off = 32; off > 0; off >>= 1) m = fmaxf(m, __shfl_down(m, off, 64));
    if ((tid & 63) == 0) wmax[tid >> 6] = m;
    __syncthreads();
    if (tid == 0)
        slots[blk] = fmaxf(fmaxf(wmax[0], wmax[1]), fmaxf(wmax[2], wmax[3]));
}

// Pass B: reduce slots -> inv, recompute FIR, scale, write (nontemporal).
__global__ __launch_bounds__(256) void fdn_write(
    const float* __restrict__ x, const float* __restrict__ g,
    const float* __restrict__ Q, const float* __restrict__ slots,
    float* __restrict__ out) {
    __shared__ __align__(16) float smem[LDSF];
    __shared__ float csh[8];
    __shared__ float wmax[4];

    const int tid = threadIdx.x;
    const int blk = swz(blockIdx.x);

    load_coeffs(g, Q, csh, tid);

    // each thread covers 4 of the 1024 slots (one float4 load)
    float4 s0 = *(const float4*)(slots + tid * 4);

    stage(x, smem, blk, tid);

    float m = fmaxf(fmaxf(s0.x, s0.y), fmaxf(s0.z, s0.w));
#pragma unroll
    for (int off = 32; off > 0; off >>= 1) m = fmaxf(m, __shfl_down(m, off, 64));
    if ((tid & 63) == 0) wmax[tid >> 6] = m;
    __syncthreads();   // covers staging + wmax

    const float inv = 1.0f / fmaxf(fmaxf(wmax[0], wmax[1]),
                                   fmaxf(wmax[2], wmax[3]));
    float c[8];
#pragma unroll
    for (int n = 0; n < 8; ++n) c[n] = csh[n];

    const int base = blk * CHUNK;
#pragma unroll
    for (int i = 0; i < CHUNK / 1024; ++i) {
        const int j = i * 1024 + tid * 4;
        const float* p = smem + HALO + j;
        float4 o = quad_fir(p, c);
        floatx4 ov;
        ov.x = o.x * inv; ov.y = o.y * inv;
        ov.z = o.z * inv; ov.w = o.w * inv;
        __builtin_nontemporal_store(ov, (floatx4*)(out + base + j));
    }
}

extern "C" void kernel_launch(void* const* d_in, const int* in_sizes, int n_in,
                              void* d_out, int out_size, void* d_ws, size_t ws_size,
                              hipStream_t stream) {
    const float* x = (const float*)d_in[0];       // input_sig [1, T]
    const float* g = (const float*)d_in[1];       // feedback_gain [8]
    const float* Q = (const float*)d_in[2];       // orthogonal_matrix [8,8]
    float* out = (float*)d_out;
    float* slots = (float*)d_ws;                  // 1024 per-block maxes
                                                  // (written unconditionally by
                                                  //  pass A before pass B reads)

    fdn_max  <<<dim3(NBLK), dim3(256), 0, stream>>>(x, g, Q, slots);
    fdn_write<<<dim3(NBLK), dim3(256), 0, stream>>>(x, g, Q, slots, out);
}

// Round 9
// 106.972 us; speedup vs baseline: 1.0162x; 1.0162x over previous
//
#include <hip/hip_runtime.h>

// FDN reverb == 8-tap sparse FIR + 50/50 mix + global max-abs normalize.
// Plain stream-ordered two-pass (cooperative grid.sync measured ~100us of
// overhead in R3/R4 — do not use):
//   pass A: LDS-staged FIR, block max only -> slots[blk]  (no 32MB store)
//   pass B: reduce slots -> 1/max, recompute FIR, scale, single 32MB write
// LDS reads exploit delay parity: D1,D2,D6 = 0 mod 4 -> ds_read_b128,
// D4 = 2 mod 4 -> 2x ds_read_b64, D0,D3,D5,D7 = 1 mod 4 -> b32+b64+b32.
// CHUNK=4096 / 31KB LDS / 5 blocks/CU is measured optimal (8192 @ 3 blocks/CU
// regressed: staging needs the occupancy more than it needs less halo traffic).
// Block swizzle: give each XCD a contiguous 4MB region of x (== its L2).
#define T_LEN 8388608
#define CHUNK 4096               // outputs per block
#define HALO  3840               // >= max delay (3825), multiple of 4
#define LDSF  (HALO + CHUNK)     // 7936 floats = 31744 B -> 5 blocks/CU
#define NBLK  (T_LEN / CHUNK)    // 2048 blocks

#define D0 1425   // %4 == 1
#define D1 1780   // %4 == 0
#define D2 1972   // %4 == 0
#define D3 2097   // %4 == 1
#define D4 2558   // %4 == 2
#define D5 2961   // %4 == 1
#define D6 3508   // %4 == 0
#define D7 3825   // %4 == 1

typedef float floatx4 __attribute__((ext_vector_type(4)));  // native vec for
                                                            // nontemporal store

__device__ __forceinline__ int swz(int b) {
    // phys block -> logical chunk: XCD k (b%8) owns contiguous [k*256,(k+1)*256)
    return (b & 7) * (NBLK / 8) + (b >> 3);
}

__device__ __forceinline__ void load_odd(const float* q, float* v) {
    // q is (3 mod 4)-dword aligned: scalar, aligned float2, scalar
    float  a  = q[0];
    float2 b  = *(const float2*)(q + 1);
    float  c  = q[3];
    v[0] = a; v[1] = b.x; v[2] = b.y; v[3] = c;
}

// Compute 4 outputs at LDS pointer p (16B-aligned), coefficients c[8].
__device__ __forceinline__ float4 quad_fir(const float* __restrict__ p,
                                           const float* __restrict__ c) {
    float4 dry = *(const float4*)(p);
    float4 t1  = *(const float4*)(p - D1);   // b128
    float4 t2  = *(const float4*)(p - D2);   // b128
    float4 t6  = *(const float4*)(p - D6);   // b128
    float2 t4a = *(const float2*)(p - D4);   // b64 (p-D4 is 2 mod 4)
    float2 t4b = *(const float2*)(p - D4 + 2);
    float t0v[4], t3v[4], t5v[4], t7v[4];
    load_odd(p - D0, t0v);
    load_odd(p - D3, t3v);
    load_odd(p - D5, t5v);
    load_odd(p - D7, t7v);
    float t4v[4] = {t4a.x, t4a.y, t4b.x, t4b.y};

    float4 o;
#pragma unroll
    for (int k = 0; k < 4; ++k) {
        float wet = 0.f;
        wet = fmaf(c[0], t0v[k],      wet);
        wet = fmaf(c[1], (&t1.x)[k],  wet);
        wet = fmaf(c[2], (&t2.x)[k],  wet);
        wet = fmaf(c[3], t3v[k],      wet);
        wet = fmaf(c[4], t4v[k],      wet);
        wet = fmaf(c[5], t5v[k],      wet);
        wet = fmaf(c[6], (&t6.x)[k],  wet);
        wet = fmaf(c[7], t7v[k],      wet);
        (&o.x)[k] = fmaf(0.5f, wet, 0.5f * (&dry.x)[k]);
    }
    return o;
}

// Stage [blk*CHUNK - HALO, blk*CHUNK + CHUNK) into LDS; zeros before t=0.
__device__ __forceinline__ void stage(const float* __restrict__ x, float* smem,
                                      int blk, int tid) {
    const long gs = (long)blk * CHUNK - HALO;
    for (int v4 = tid; v4 < LDSF / 4; v4 += 256) {
        long ga = gs + (long)v4 * 4;
        float4 val = make_float4(0.f, 0.f, 0.f, 0.f);
        if (ga >= 0) val = *(const float4*)(x + ga);
        *(float4*)(smem + v4 * 4) = val;
    }
}

__device__ __forceinline__ void load_coeffs(const float* __restrict__ g,
                                            const float* __restrict__ Q,
                                            float* csh, int tid) {
    if (tid < 8) {
        float s = 0.f;
#pragma unroll
        for (int j = 0; j < 8; ++j) s += Q[j * 8 + tid];
        csh[tid] = s * g[tid];
    }
}

// Pass A: FIR + block max -> slots[blk]. No output store.
__global__ __launch_bounds__(256) void fdn_max(
    const float* __restrict__ x, const float* __restrict__ g,
    const float* __restrict__ Q, float* __restrict__ slots) {
    __shared__ __align__(16) float smem[LDSF];
    __shared__ float csh[8];
    __shared__ float wmax[4];

    const int tid = threadIdx.x;
    const int blk = swz(blockIdx.x);

    load_coeffs(g, Q, csh, tid);
    stage(x, smem, blk, tid);
    __syncthreads();

    float c[8];
#pragma unroll
    for (int n = 0; n < 8; ++n) c[n] = csh[n];

    float m = 0.f;
#pragma unroll
    for (int i = 0; i < CHUNK / 1024; ++i) {
        const float* p = smem + HALO + i * 1024 + tid * 4;
        float4 o = quad_fir(p, c);
        m = fmaxf(m, fmaxf(fmaxf(fabsf(o.x), fabsf(o.y)),
                           fmaxf(fabsf(o.z), fabsf(o.w))));
    }

#pragma unroll
    for (int off = 32; off > 0; off >>= 1) m = fmaxf(m, __shfl_down(m, off, 64));
    if ((tid & 63) == 0) wmax[tid >> 6] = m;
    __syncthreads();
    if (tid == 0)
        slots[blk] = fmaxf(fmaxf(wmax[0], wmax[1]), fmaxf(wmax[2], wmax[3]));
}

// Pass B: reduce slots -> inv, recompute FIR, scale, write (nontemporal).
__global__ __launch_bounds__(256) void fdn_write(
    const float* __restrict__ x, const float* __restrict__ g,
    const float* __restrict__ Q, const float* __restrict__ slots,
    float* __restrict__ out) {
    __shared__ __align__(16) float smem[LDSF];
    __shared__ float csh[8];
    __shared__ float wmax[4];

    const int tid = threadIdx.x;
    const int blk = swz(blockIdx.x);

    load_coeffs(g, Q, csh, tid);

    // each thread covers 8 of the 2048 slots (two float4 loads)
    float4 s0 = *(const float4*)(slots + tid * 8);
    float4 s1 = *(const float4*)(slots + tid * 8 + 4);

    stage(x, smem, blk, tid);

    float m = fmaxf(fmaxf(fmaxf(s0.x, s0.y), fmaxf(s0.z, s0.w)),
                    fmaxf(fmaxf(s1.x, s1.y), fmaxf(s1.z, s1.w)));
#pragma unroll
    for (int off = 32; off > 0; off >>= 1) m = fmaxf(m, __shfl_down(m, off, 64));
    if ((tid & 63) == 0) wmax[tid >> 6] = m;
    __syncthreads();   // covers staging + wmax

    const float inv = 1.0f / fmaxf(fmaxf(wmax[0], wmax[1]),
                                   fmaxf(wmax[2], wmax[3]));
    float c[8];
#pragma unroll
    for (int n = 0; n < 8; ++n) c[n] = csh[n];

    const int base = blk * CHUNK;
#pragma unroll
    for (int i = 0; i < CHUNK / 1024; ++i) {
        const int j = i * 1024 + tid * 4;
        const float* p = smem + HALO + j;
        float4 o = quad_fir(p, c);
        floatx4 ov;
        ov.x = o.x * inv; ov.y = o.y * inv;
        ov.z = o.z * inv; ov.w = o.w * inv;
        __builtin_nontemporal_store(ov, (floatx4*)(out + base + j));
    }
}

extern "C" void kernel_launch(void* const* d_in, const int* in_sizes, int n_in,
                              void* d_out, int out_size, void* d_ws, size_t ws_size,
                              hipStream_t stream) {
    const float* x = (const float*)d_in[0];       // input_sig [1, T]
    const float* g = (const float*)d_in[1];       // feedback_gain [8]
    const float* Q = (const float*)d_in[2];       // orthogonal_matrix [8,8]
    float* out = (float*)d_out;
    float* slots = (float*)d_ws;                  // 2048 per-block maxes
                                                  // (written unconditionally by
                                                  //  pass A before pass B reads)

    fdn_max  <<<dim3(NBLK), dim3(256), 0, stream>>>(x, g, Q, slots);
    fdn_write<<<dim3(NBLK), dim3(256), 0, stream>>>(x, g, Q, slots, out);
}